// Round 1
// baseline (245.796 us; speedup 1.0000x reference)
//
#include <hip/hip_runtime.h>
#include <hip/hip_bf16.h>
#include <math.h>

// Problem constants
#define BQ 128
#define PP 256
#define MQ 16
#define MP 32
#define DD 768
#define MROWS (BQ*MQ)   // 2048
#define NROWS (PP*MP)   // 8192

typedef __bf16 bf16x8 __attribute__((ext_vector_type(8)));
typedef float  f32x4  __attribute__((ext_vector_type(4)));

// ---------- fp32 -> bf16 RTNE ----------
__device__ inline ushort bf16r(float f) {
    unsigned u = __float_as_uint(f);
    return (ushort)((u + 0x7FFFu + ((u >> 16) & 1u)) >> 16);
}

__global__ void conv_bf16_v4(const float4* __restrict__ in, ushort4* __restrict__ out, int n4) {
    int idx = blockIdx.x * blockDim.x + threadIdx.x;
    if (idx < n4) {
        float4 x = in[idx];
        ushort4 o;
        o.x = bf16r(x.x); o.y = bf16r(x.y); o.z = bf16r(x.z); o.w = bf16r(x.w);
        out[idx] = o;
    }
}

// ---------- bf16 MFMA GEMM: C[M,N] = A[M,K] * B[N,K]^T ----------
#define BM 128
#define BN 128
#define BK 32
#define LDK 40   // padded LDS row stride in ushorts (80B: 2-way bank alias only, free)

__global__ __launch_bounds__(256) void gemm_bt(const ushort* __restrict__ A,
                                               const ushort* __restrict__ B,
                                               float* __restrict__ C) {
    __shared__ ushort sA[BM * LDK];
    __shared__ ushort sB[BN * LDK];
    const int tid  = threadIdx.x;
    const int lane = tid & 63;
    const int wid  = tid >> 6;        // 4 waves
    const int wr   = wid >> 1;        // wave row 0..1
    const int wc   = wid & 1;         // wave col 0..1
    const int tileM = blockIdx.y * BM;
    const int tileN = blockIdx.x * BN;

    f32x4 acc[4][4];
    #pragma unroll
    for (int i = 0; i < 4; ++i)
        #pragma unroll
        for (int j = 0; j < 4; ++j) {
            f32x4 z = {0.f, 0.f, 0.f, 0.f};
            acc[i][j] = z;
        }

    const int r0 = lane & 15;   // fragment row (m or n) within 16
    const int q  = lane >> 4;   // k-quad 0..3

    for (int k0 = 0; k0 < DD; k0 += BK) {
        // stage: 128x32 bf16 = 512 chunks of 8 elems (16B); 256 threads x 2
        #pragma unroll
        for (int it = 0; it < 2; ++it) {
            int c   = tid + it * 256;       // 0..511
            int row = c >> 2;
            int kc  = (c & 3) << 3;
            const uint4* gA = (const uint4*)(A + (size_t)(tileM + row) * DD + k0 + kc);
            *(uint4*)(&sA[row * LDK + kc]) = *gA;
            const uint4* gB = (const uint4*)(B + (size_t)(tileN + row) * DD + k0 + kc);
            *(uint4*)(&sB[row * LDK + kc]) = *gB;
        }
        __syncthreads();

        bf16x8 af[4], bfr[4];
        #pragma unroll
        for (int mi = 0; mi < 4; ++mi)
            af[mi] = *(const bf16x8*)(&sA[(wr * 64 + mi * 16 + r0) * LDK + q * 8]);
        #pragma unroll
        for (int ni = 0; ni < 4; ++ni)
            bfr[ni] = *(const bf16x8*)(&sB[(wc * 64 + ni * 16 + r0) * LDK + q * 8]);

        #pragma unroll
        for (int mi = 0; mi < 4; ++mi)
            #pragma unroll
            for (int ni = 0; ni < 4; ++ni)
                acc[mi][ni] = __builtin_amdgcn_mfma_f32_16x16x32_bf16(af[mi], bfr[ni], acc[mi][ni], 0, 0, 0);
        __syncthreads();
    }

    // epilogue: C/D layout col = lane&15, row = (lane>>4)*4 + reg  [m89-verified]
    #pragma unroll
    for (int mi = 0; mi < 4; ++mi) {
        #pragma unroll
        for (int ni = 0; ni < 4; ++ni) {
            int col   = tileN + wc * 64 + ni * 16 + (lane & 15);
            int rbase = tileM + wr * 64 + mi * 16 + (lane >> 4) * 4;
            #pragma unroll
            for (int r = 0; r < 4; ++r)
                C[(size_t)(rbase + r) * NROWS + col] = acc[mi][ni][r];
        }
    }
}

// ---------- dual top-k selection, one wave per (b,p) pair ----------
__device__ inline float key_to_float(unsigned kk) {
    return (kk & 0x80000000u) ? __uint_as_float(kk & 0x7FFFFFFFu)
                              : __uint_as_float(~kk);
}

__device__ inline float softplus_f(float x) {
    return (x > 20.f) ? x : log1pf(expf(x));
}

__global__ __launch_bounds__(256) void select_topk(const float* __restrict__ sim,
                                                   const int* __restrict__ qm,
                                                   const int* __restrict__ pm,
                                                   const float* __restrict__ araw,
                                                   const float* __restrict__ braw,
                                                   float* __restrict__ logits) {
    const int w    = blockIdx.x * 4 + (threadIdx.x >> 6);   // pair id, 0..32767
    const int lane = threadIdx.x & 63;
    const int b = w >> 8;
    const int p = w & 255;

    // valid counts via ballot
    bool mq = (lane < MQ) && (qm[b * MQ + lane] != 0);
    int nq = __popcll(__ballot(mq));
    bool mp = (lane < MP) && (pm[p * MP + lane] != 0);
    int np_ = __popcll(__ballot(mp));
    int n = nq * np_;                 // >= 1 guaranteed
    int k = (4 * n) / 10; if (k < 1) k = 1;
    int l = (8 * n) / 10;             // min with n is redundant

    // 8 values per lane: i = lane/4, j = (lane%4)*8 + t
    const int i  = lane >> 2;
    const int j0 = (lane & 3) << 3;
    const float4* vp = (const float4*)(sim + (size_t)(b * MQ + i) * NROWS + p * MP + j0);
    float4 va = vp[0], vb = vp[1];
    float v[8] = {va.x, va.y, va.z, va.w, vb.x, vb.y, vb.z, vb.w};

    int qv = qm[b * MQ + i];
    const int4* pmp = (const int4*)(pm + p * MP + j0);
    int4 pa = pmp[0], pb2 = pmp[1];
    int pj[8] = {pa.x, pa.y, pa.z, pa.w, pb2.x, pb2.y, pb2.z, pb2.w};

    // order-preserving uint keys; invalid -> 0 (never selected: thresholds end >= 1)
    unsigned key[8], key2[8];
    #pragma unroll
    for (int t = 0; t < 8; ++t) {
        unsigned u  = __float_as_uint(v[t]);
        unsigned kk = (u & 0x80000000u) ? ~u : (u | 0x80000000u);
        bool val = (qv != 0) && (pj[t] != 0);
        key[t]  = val ? kk  : 0u;
        key2[t] = val ? ~kk : 0u;
    }

    // MSB-first radix descent for k-th largest key (top) and l-th largest key2 (bottom)
    unsigned T1 = 0u, T2 = 0u;
    for (int bit = 31; bit >= 0; --bit) {
        unsigned c1 = T1 | (1u << bit);
        unsigned c2 = T2 | (1u << bit);
        int cnt = 0;
        #pragma unroll
        for (int t = 0; t < 8; ++t) {
            cnt += (key[t]  >= c1) ? 1 : 0;
            cnt += (key2[t] >= c2) ? 0x10000 : 0;
        }
        #pragma unroll
        for (int off = 32; off > 0; off >>= 1)
            cnt += __shfl_xor(cnt, off, 64);
        if ((cnt & 0xFFFF) >= k) T1 = c1;
        if ((cnt >> 16)    >= l) T2 = c2;
    }

    // sums of strictly-above-threshold elements + tie correction
    float S1 = 0.f, S2 = 0.f;
    int cc = 0;
    #pragma unroll
    for (int t = 0; t < 8; ++t) {
        if (key[t]  > T1) { S1 += v[t]; cc += 1; }
        if (key2[t] > T2) { S2 += v[t]; cc += 0x10000; }
    }
    #pragma unroll
    for (int off = 32; off > 0; off >>= 1) {
        S1 += __shfl_xor(S1, off, 64);
        S2 += __shfl_xor(S2, off, 64);
        cc += __shfl_xor(cc, off, 64);
    }
    int c1n = cc & 0xFFFF, c2n = cc >> 16;

    float f1 = key_to_float(T1);
    float f2 = key_to_float(~T2);
    float top = S1 + (float)(k - c1n) * f1;
    float bot = (l > 0) ? (S2 + (float)(l - c2n) * f2) : 0.f;

    float a   = softplus_f(araw[0]);
    float bta = softplus_f(braw[0]);
    if (lane == 0) logits[b * PP + p] = a * top - bta * bot;
}

// ---------- loss = mean_b (lse(logits[b,:]) - logits[b,b]) ----------
__global__ __launch_bounds__(256) void loss_kernel(const float* __restrict__ logits,
                                                   float* __restrict__ loss_out) {
    __shared__ float warr[4];
    const int lane = threadIdx.x & 63;
    const int wid  = threadIdx.x >> 6;
    float acc = 0.f;
    for (int r = wid; r < BQ; r += 4) {
        const float* row = logits + r * PP;
        float x0 = row[lane], x1 = row[lane + 64], x2 = row[lane + 128], x3 = row[lane + 192];
        float m = fmaxf(fmaxf(x0, x1), fmaxf(x2, x3));
        #pragma unroll
        for (int off = 32; off > 0; off >>= 1)
            m = fmaxf(m, __shfl_xor(m, off, 64));
        float s = expf(x0 - m) + expf(x1 - m) + expf(x2 - m) + expf(x3 - m);
        #pragma unroll
        for (int off = 32; off > 0; off >>= 1)
            s += __shfl_xor(s, off, 64);
        float lse = m + logf(s);
        float diag = row[r];
        acc += (lse - diag);
    }
    if (lane == 0) warr[wid] = acc;
    __syncthreads();
    if (threadIdx.x == 0)
        loss_out[0] = (warr[0] + warr[1] + warr[2] + warr[3]) / (float)BQ;
}

extern "C" void kernel_launch(void* const* d_in, const int* in_sizes, int n_in,
                              void* d_out, int out_size, void* d_ws, size_t ws_size,
                              hipStream_t stream) {
    const float* q  = (const float*)d_in[0];
    const float* pe = (const float*)d_in[1];
    const int*   qm = (const int*)d_in[2];
    const int*   pm = (const int*)d_in[3];
    const float* ar = (const float*)d_in[4];
    const float* br = (const float*)d_in[5];
    float* out = (float*)d_out;           // [0] = loss, [1..32768] = logits

    // workspace layout: qb (3,145,728 B) | pb (12,582,912 B) | sim (67,108,864 B)
    char* ws = (char*)d_ws;
    ushort* qb  = (ushort*)ws;
    ushort* pb  = (ushort*)(ws + (size_t)MROWS * DD * 2);
    float*  sim = (float*)(ws + (size_t)MROWS * DD * 2 + (size_t)NROWS * DD * 2);

    // 1) convert fp32 -> bf16
    int nq4 = MROWS * DD / 4;   // 393216
    int np4 = NROWS * DD / 4;   // 1572864
    conv_bf16_v4<<<(nq4 + 255) / 256, 256, 0, stream>>>((const float4*)q,  (ushort4*)qb, nq4);
    conv_bf16_v4<<<(np4 + 255) / 256, 256, 0, stream>>>((const float4*)pe, (ushort4*)pb, np4);

    // 2) sim = Q * P^T  (2048 x 8192, K=768)
    dim3 gg(NROWS / BN, MROWS / BM, 1);   // (64, 16)
    gemm_bt<<<gg, 256, 0, stream>>>(qb, pb, sim);

    // 3) dual top-k -> logits
    select_topk<<<(BQ * PP) / 4, 256, 0, stream>>>(sim, qm, pm, ar, br, out + 1);

    // 4) loss
    loss_kernel<<<1, 256, 0, stream>>>(out + 1, out);
}

// Round 2
// 228.634 us; speedup vs baseline: 1.0751x; 1.0751x over previous
//
#include <hip/hip_runtime.h>
#include <hip/hip_bf16.h>
#include <math.h>

// Problem constants
#define BQ 128
#define PP 256
#define MQ 16
#define MP 32
#define DD 768
#define MROWS (BQ*MQ)   // 2048
#define NROWS (PP*MP)   // 8192

typedef __bf16 bf16x8 __attribute__((ext_vector_type(8)));
typedef float  f32x4  __attribute__((ext_vector_type(4)));

// ---------- fp32 -> bf16 RTNE ----------
__device__ inline ushort bf16r(float f) {
    unsigned u = __float_as_uint(f);
    return (ushort)((u + 0x7FFFu + ((u >> 16) & 1u)) >> 16);
}

__global__ void conv_bf16_v4(const float4* __restrict__ in, ushort4* __restrict__ out, int n4) {
    int idx = blockIdx.x * blockDim.x + threadIdx.x;
    if (idx < n4) {
        float4 x = in[idx];
        ushort4 o;
        o.x = bf16r(x.x); o.y = bf16r(x.y); o.z = bf16r(x.z); o.w = bf16r(x.w);
        out[idx] = o;
    }
}

// ---------- bf16 MFMA GEMM: C[M,N] = A[M,K] * B[N,K]^T ----------
// global_load_lds (16B) staging; unpadded 64B rows with XOR slot swizzle:
// physical 16B slot of logical k-quad q in row r is q ^ ((r>>1)&3) ->
// every 16-lane read cohort spans all 32 banks at 2-way (free, m136).
#define BM 128
#define BN 128
#define BK 32
#define LDSU 32   // ushorts per LDS row (64 B, unpadded)

__device__ inline void load16_to_lds(const ushort* g, ushort* l) {
    __builtin_amdgcn_global_load_lds(
        (const __attribute__((address_space(1))) unsigned int*)(g),
        (__attribute__((address_space(3))) unsigned int*)(l),
        16, 0, 0);
}

__global__ __launch_bounds__(256) void gemm_bt(const ushort* __restrict__ A,
                                               const ushort* __restrict__ B,
                                               float* __restrict__ C) {
    __shared__ ushort sA[BM * LDSU];   // 8 KB
    __shared__ ushort sB[BN * LDSU];   // 8 KB
    const int tid  = threadIdx.x;
    const int lane = tid & 63;
    const int wid  = tid >> 6;        // 4 waves
    const int wr   = wid >> 1;        // wave row 0..1
    const int wc   = wid & 1;         // wave col 0..1
    const int tileM = blockIdx.y * BM;
    const int tileN = blockIdx.x * BN;

    f32x4 acc[4][4];
    #pragma unroll
    for (int i = 0; i < 4; ++i)
        #pragma unroll
        for (int j = 0; j < 4; ++j) {
            f32x4 z = {0.f, 0.f, 0.f, 0.f};
            acc[i][j] = z;
        }

    // staging geometry: wave stages 16-row chunks; lane -> (row, physical slot)
    const int lr    = lane >> 2;                         // row within chunk
    const int kcu   = ((lane & 3) ^ ((lane >> 3) & 3)) << 3;  // logical ushort k-offset (swizzled)

    // read geometry
    const int r0    = lane & 15;
    const int q     = lane >> 4;
    const int physq = q ^ ((r0 >> 1) & 3);               // physical slot for logical q

    for (int k0 = 0; k0 < DD; k0 += BK) {
        #pragma unroll
        for (int c = 0; c < 2; ++c) {
            int chunk = wid + c * 4;                     // 0..7
            int row   = chunk * 16 + lr;
            load16_to_lds(A + (size_t)(tileM + row) * DD + k0 + kcu, &sA[chunk * 16 * LDSU]);
            load16_to_lds(B + (size_t)(tileN + row) * DD + k0 + kcu, &sB[chunk * 16 * LDSU]);
        }
        __syncthreads();

        bf16x8 af[4], bfr[4];
        #pragma unroll
        for (int mi = 0; mi < 4; ++mi)
            af[mi] = *(const bf16x8*)(&sA[(wr * 64 + mi * 16 + r0) * LDSU + physq * 8]);
        #pragma unroll
        for (int ni = 0; ni < 4; ++ni)
            bfr[ni] = *(const bf16x8*)(&sB[(wc * 64 + ni * 16 + r0) * LDSU + physq * 8]);

        #pragma unroll
        for (int mi = 0; mi < 4; ++mi)
            #pragma unroll
            for (int ni = 0; ni < 4; ++ni)
                acc[mi][ni] = __builtin_amdgcn_mfma_f32_16x16x32_bf16(af[mi], bfr[ni], acc[mi][ni], 0, 0, 0);
        __syncthreads();
    }

    // epilogue: C/D layout col = lane&15, row = (lane>>4)*4 + reg  [m89-verified]
    #pragma unroll
    for (int mi = 0; mi < 4; ++mi) {
        #pragma unroll
        for (int ni = 0; ni < 4; ++ni) {
            int col   = tileN + wc * 64 + ni * 16 + (lane & 15);
            int rbase = tileM + wr * 64 + mi * 16 + (lane >> 4) * 4;
            #pragma unroll
            for (int r = 0; r < 4; ++r)
                C[(size_t)(rbase + r) * NROWS + col] = acc[mi][ni][r];
        }
    }
}

// ---------- dual top-k selection, one wave per (b,p) pair ----------
// Counting via ballot+popcount (scalar pipe) instead of shfl butterflies:
// the per-bit count is wave-uniform, so __ballot -> s_bcnt1 avoids the
// 6-deep ds_bpermute latency chain per radix bit.
__device__ inline float key_to_float(unsigned kk) {
    return (kk & 0x80000000u) ? __uint_as_float(kk & 0x7FFFFFFFu)
                              : __uint_as_float(~kk);
}

__device__ inline float softplus_f(float x) {
    return (x > 20.f) ? x : log1pf(expf(x));
}

__global__ __launch_bounds__(256) void select_topk(const float* __restrict__ sim,
                                                   const int* __restrict__ qm,
                                                   const int* __restrict__ pm,
                                                   const float* __restrict__ araw,
                                                   const float* __restrict__ braw,
                                                   float* __restrict__ logits) {
    const int w    = blockIdx.x * 4 + (threadIdx.x >> 6);   // pair id, 0..32767
    const int lane = threadIdx.x & 63;
    const int b = w >> 8;
    const int p = w & 255;

    // valid counts via ballot
    bool mq = (lane < MQ) && (qm[b * MQ + lane] != 0);
    int nq = __popcll(__ballot(mq));
    bool mp = (lane < MP) && (pm[p * MP + lane] != 0);
    int np_ = __popcll(__ballot(mp));
    int n = nq * np_;                 // >= 1 guaranteed
    int k = (4 * n) / 10; if (k < 1) k = 1;
    int l = (8 * n) / 10;

    // 8 values per lane: i = lane/4, j = (lane%4)*8 + t
    const int i  = lane >> 2;
    const int j0 = (lane & 3) << 3;
    const float4* vp = (const float4*)(sim + (size_t)(b * MQ + i) * NROWS + p * MP + j0);
    float4 va = vp[0], vb = vp[1];
    float v[8] = {va.x, va.y, va.z, va.w, vb.x, vb.y, vb.z, vb.w};

    int qv = qm[b * MQ + i];
    const int4* pmp = (const int4*)(pm + p * MP + j0);
    int4 pa = pmp[0], pb2 = pmp[1];
    int pj[8] = {pa.x, pa.y, pa.z, pa.w, pb2.x, pb2.y, pb2.z, pb2.w};

    // order-preserving uint keys; invalid -> 0 (never selected: thresholds end >= 1)
    unsigned key[8], key2[8];
    #pragma unroll
    for (int t = 0; t < 8; ++t) {
        unsigned u  = __float_as_uint(v[t]);
        unsigned kk = (u & 0x80000000u) ? ~u : (u | 0x80000000u);
        bool val = (qv != 0) && (pj[t] != 0);
        key[t]  = val ? kk  : 0u;
        key2[t] = val ? ~kk : 0u;
    }

    // MSB-first radix descent: k-th largest key (top), l-th largest key2 (bottom)
    unsigned T1 = 0u, T2 = 0u;
    for (int bit = 31; bit >= 0; --bit) {
        unsigned c1 = T1 | (1u << bit);
        unsigned c2 = T2 | (1u << bit);
        int cnt1 = 0, cnt2 = 0;
        #pragma unroll
        for (int t = 0; t < 8; ++t) {
            cnt1 += __popcll(__ballot(key[t]  >= c1));
            cnt2 += __popcll(__ballot(key2[t] >= c2));
        }
        if (cnt1 >= k) T1 = c1;
        if (cnt2 >= l) T2 = c2;
    }

    // sums of strictly-above-threshold elements + tie correction
    float S1 = 0.f, S2 = 0.f;
    int c1n = 0, c2n = 0;
    #pragma unroll
    for (int t = 0; t < 8; ++t) {
        if (key[t]  > T1) S1 += v[t];
        if (key2[t] > T2) S2 += v[t];
        c1n += __popcll(__ballot(key[t]  > T1));
        c2n += __popcll(__ballot(key2[t] > T2));
    }
    #pragma unroll
    for (int off = 32; off > 0; off >>= 1) {
        S1 += __shfl_xor(S1, off, 64);
        S2 += __shfl_xor(S2, off, 64);
    }

    float f1 = key_to_float(T1);
    float f2 = key_to_float(~T2);
    float top = S1 + (float)(k - c1n) * f1;
    float bot = (l > 0) ? (S2 + (float)(l - c2n) * f2) : 0.f;

    float a   = softplus_f(araw[0]);
    float bta = softplus_f(braw[0]);
    if (lane == 0) logits[b * PP + p] = a * top - bta * bot;
}

// ---------- loss = mean_b (lse(logits[b,:]) - logits[b,b]) ----------
__global__ __launch_bounds__(256) void loss_kernel(const float* __restrict__ logits,
                                                   float* __restrict__ loss_out) {
    __shared__ float warr[4];
    const int lane = threadIdx.x & 63;
    const int wid  = threadIdx.x >> 6;
    float acc = 0.f;
    for (int r = wid; r < BQ; r += 4) {
        const float* row = logits + r * PP;
        float x0 = row[lane], x1 = row[lane + 64], x2 = row[lane + 128], x3 = row[lane + 192];
        float m = fmaxf(fmaxf(x0, x1), fmaxf(x2, x3));
        #pragma unroll
        for (int off = 32; off > 0; off >>= 1)
            m = fmaxf(m, __shfl_xor(m, off, 64));
        float s = expf(x0 - m) + expf(x1 - m) + expf(x2 - m) + expf(x3 - m);
        #pragma unroll
        for (int off = 32; off > 0; off >>= 1)
            s += __shfl_xor(s, off, 64);
        float lse = m + logf(s);
        float diag = row[r];
        acc += (lse - diag);
    }
    if (lane == 0) warr[wid] = acc;
    __syncthreads();
    if (threadIdx.x == 0)
        loss_out[0] = (warr[0] + warr[1] + warr[2] + warr[3]) / (float)BQ;
}

extern "C" void kernel_launch(void* const* d_in, const int* in_sizes, int n_in,
                              void* d_out, int out_size, void* d_ws, size_t ws_size,
                              hipStream_t stream) {
    const float* q  = (const float*)d_in[0];
    const float* pe = (const float*)d_in[1];
    const int*   qm = (const int*)d_in[2];
    const int*   pm = (const int*)d_in[3];
    const float* ar = (const float*)d_in[4];
    const float* br = (const float*)d_in[5];
    float* out = (float*)d_out;           // [0] = loss, [1..32768] = logits

    // workspace layout: qb | pb | sim
    char* ws = (char*)d_ws;
    ushort* qb  = (ushort*)ws;
    ushort* pb  = (ushort*)(ws + (size_t)MROWS * DD * 2);
    float*  sim = (float*)(ws + (size_t)MROWS * DD * 2 + (size_t)NROWS * DD * 2);

    // 1) convert fp32 -> bf16
    int nq4 = MROWS * DD / 4;
    int np4 = NROWS * DD / 4;
    conv_bf16_v4<<<(nq4 + 255) / 256, 256, 0, stream>>>((const float4*)q,  (ushort4*)qb, nq4);
    conv_bf16_v4<<<(np4 + 255) / 256, 256, 0, stream>>>((const float4*)pe, (ushort4*)pb, np4);

    // 2) sim = Q * P^T  (2048 x 8192, K=768)
    dim3 gg(NROWS / BN, MROWS / BM, 1);   // (64, 16)
    gemm_bt<<<gg, 256, 0, stream>>>(qb, pb, sim);

    // 3) dual top-k -> logits
    select_topk<<<(BQ * PP) / 4, 256, 0, stream>>>(sim, qm, pm, ar, br, out + 1);

    // 4) loss
    loss_kernel<<<1, 256, 0, stream>>>(out + 1, out);
}